// Round 3
// baseline (120.495 us; speedup 1.0000x reference)
//
#include <hip/hip_runtime.h>

#define T_LEN 8192
#define FLOOR_C 1e-6f

typedef float f4 __attribute__((ext_vector_type(4)));

__device__ __forceinline__ float flog2(float v) { return __builtin_amdgcn_logf(v); }
__device__ __forceinline__ float fexp2(float v) { return __builtin_amdgcn_exp2f(v); }

__global__ __launch_bounds__(256) void pcen_kernel(
    const float* __restrict__ x,
    const float* __restrict__ alpha_p,
    const float* __restrict__ delta_p,
    const float* __restrict__ root_p,
    const float* __restrict__ sc_p,
    float* __restrict__ out,
    int nrows)
{
    const float alpha = alpha_p[0];
    const float delta = delta_p[0];
    const float root  = root_p[0];
    float s = sc_p[0];
    s = fminf(fmaxf(s, 0.001f), 0.999f);
    const float oms = 1.0f - s;

    const int wave = threadIdx.x >> 6;
    const int lane = threadIdx.x & 63;
    const int row  = blockIdx.x * 4 + wave;
    if (row >= nrows) return;

    // scan multipliers: per-lane span is 8 elements -> factor s^8
    const float s2 = s * s;
    const float s4 = s2 * s2;
    const float s8 = s4 * s4;
    const float m0 = s8;          // s^8
    const float m1 = m0 * m0;     // s^16
    const float m2 = m1 * m1;     // s^32
    const float m3 = m2 * m2;     // s^64
    const float m4 = m3 * m3;     // s^128
    const float m5 = m4 * m4;     // s^256
    const float s512 = m5 * m5;   // s^512 (whole-chunk factor)
    // s^(8*lane), once per thread (s>0 so log2 safe)
    const float sp8i = fexp2(8.0f * (float)lane * flog2(s));
    const bool  root_is_half = (root == 0.5f);
    const float droot = root_is_half ? sqrtf(delta)
                                     : fexp2(root * flog2(delta));

    const f4* __restrict__ xrow = (const f4*)(x + (size_t)row * T_LEN);
    f4* __restrict__ orow = (f4*)(out + (size_t)row * T_LEN);

    const int nchunks = T_LEN / 512;  // 16 iterations, 512 elems per wave-chunk
    float carry = 0.0f;               // smoothed value just before current chunk

    // prefetch chunk 0 (2 x float4 = 32 B/lane, 2 KB/wave in flight)
    f4 a0 = __builtin_nontemporal_load(xrow + lane * 2);
    f4 a1 = __builtin_nontemporal_load(xrow + lane * 2 + 1);

    for (int c = 0; c < nchunks; ++c) {
        f4 n0, n1;
        if (c + 1 < nchunks) {
            n0 = __builtin_nontemporal_load(xrow + (c + 1) * 128 + lane * 2);
            n1 = __builtin_nontemporal_load(xrow + (c + 1) * 128 + lane * 2 + 1);
        }

        float xv[8] = {a0.x, a0.y, a0.z, a0.w, a1.x, a1.y, a1.z, a1.w};

        // Local affine map over this lane's 8 elements: f(p) = s^8*p + B
        float B = xv[0];
        #pragma unroll
        for (int i = 1; i < 8; ++i) B = B * s + xv[i];
        B *= oms;

        // Inclusive wave scan (Hillis-Steele), per-step factor s^8
        float P = B;
        float t;
        t = __shfl_up(P, 1);  if (lane >= 1)  P += m0 * t;
        t = __shfl_up(P, 2);  if (lane >= 2)  P += m1 * t;
        t = __shfl_up(P, 4);  if (lane >= 4)  P += m2 * t;
        t = __shfl_up(P, 8);  if (lane >= 8)  P += m3 * t;
        t = __shfl_up(P, 16); if (lane >= 16) P += m4 * t;
        t = __shfl_up(P, 32); if (lane >= 32) P += m5 * t;

        // Exclusive prefix
        float X = __shfl_up(P, 1);
        if (lane == 0) X = 0.0f;

        // State entering this lane's first element
        float state = sp8i * carry + X;

        // Carry to next chunk
        float Plast = __shfl(P, 63);
        carry = s512 * carry + Plast;

        // Sequential EMA (exact) + PCEN per element
        float o[8];
        float sm = state;
        #pragma unroll
        for (int i = 0; i < 8; ++i) {
            sm = s * sm + oms * xv[i];
            float st = fexp2(-alpha * flog2(FLOOR_C + sm));
            float inner = xv[i] * st + delta;
            float pr = root_is_half ? sqrtf(inner) : fexp2(root * flog2(inner));
            o[i] = pr - droot;
        }

        f4 o0 = {o[0], o[1], o[2], o[3]};
        f4 o1 = {o[4], o[5], o[6], o[7]};
        __builtin_nontemporal_store(o0, orow + c * 128 + lane * 2);
        __builtin_nontemporal_store(o1, orow + c * 128 + lane * 2 + 1);

        a0 = n0;
        a1 = n1;
    }
}

extern "C" void kernel_launch(void* const* d_in, const int* in_sizes, int n_in,
                              void* d_out, int out_size, void* d_ws, size_t ws_size,
                              hipStream_t stream) {
    const float* x       = (const float*)d_in[0];
    const float* alpha_p = (const float*)d_in[1];
    const float* delta_p = (const float*)d_in[2];
    const float* root_p  = (const float*)d_in[3];
    const float* sc_p    = (const float*)d_in[4];
    float* out = (float*)d_out;

    int nrows = in_sizes[0] / T_LEN;       // 64*128 = 8192 rows
    int blocks = (nrows + 3) / 4;          // 4 waves (rows) per 256-thread block

    pcen_kernel<<<blocks, 256, 0, stream>>>(x, alpha_p, delta_p, root_p, sc_p,
                                            out, nrows);
}

// Round 4
// 95.536 us; speedup vs baseline: 1.2613x; 1.2613x over previous
//
#include <hip/hip_runtime.h>

#define T_LEN 8192
#define CHUNK 256
#define FLOOR_C 1e-6f

typedef float f4 __attribute__((ext_vector_type(4)));

__device__ __forceinline__ float flog2(float v) { return __builtin_amdgcn_logf(v); }
__device__ __forceinline__ float fexp2(float v) { return __builtin_amdgcn_exp2f(v); }

__device__ __forceinline__ float pcen_one(float xv, float sm, float alpha,
                                          float delta, float root, float droot,
                                          bool root_is_half) {
    float st = fexp2(-alpha * flog2(FLOOR_C + sm));
    float inner = xv * st + delta;
    float pr = root_is_half ? sqrtf(inner) : fexp2(root * flog2(inner));
    return pr - droot;
}

__global__ __launch_bounds__(256) void pcen_kernel(
    const float* __restrict__ x,
    const float* __restrict__ alpha_p,
    const float* __restrict__ delta_p,
    const float* __restrict__ root_p,
    const float* __restrict__ sc_p,
    float* __restrict__ out,
    int nrows)
{
    const float alpha = alpha_p[0];
    const float delta = delta_p[0];
    const float root  = root_p[0];
    float s = sc_p[0];
    s = fminf(fmaxf(s, 0.001f), 0.999f);
    const float oms = 1.0f - s;

    const bool  root_is_half = (root == 0.5f);
    const float droot = root_is_half ? sqrtf(delta)
                                     : fexp2(root * flog2(delta));

    const int wave = threadIdx.x >> 6;
    const int lane = threadIdx.x & 63;
    const int gid  = blockIdx.x * 4 + wave;   // chunk id
    const int row  = gid >> 5;                // 32 chunks of 256 per row
    const int cpos = gid & 31;
    if (row >= nrows) return;

    if (s <= 0.08f) {
        // ---- Windowed path: smoothed[t] depends on <=12 predecessors to
        // fp32 precision (s^9 <= 0.08^9 ~ 1.3e-10). Zero-padded warm-up at
        // row start is EXACT (scan initial state is 0).
        const int off = cpos * CHUNK + lane * 4;      // float offset in row
        const float* p = x + (size_t)row * T_LEN + off;

        f4 xm2 = {0.f, 0.f, 0.f, 0.f};
        f4 xm1 = {0.f, 0.f, 0.f, 0.f};
        f4 xc  = *(const f4*)p;                       // own 4 elements
        if (off >= 8) xm2 = *(const f4*)(p - 8);      // window [-8,-5]
        if (off >= 4) xm1 = *(const f4*)(p - 4);      // window [-4,-1]

        // 8 warm-up EMA steps (halo), then 4 real steps with output
        float sm = 0.0f;
        sm = s * sm + oms * xm2.x;
        sm = s * sm + oms * xm2.y;
        sm = s * sm + oms * xm2.z;
        sm = s * sm + oms * xm2.w;
        sm = s * sm + oms * xm1.x;
        sm = s * sm + oms * xm1.y;
        sm = s * sm + oms * xm1.z;
        sm = s * sm + oms * xm1.w;

        f4 o;
        sm = s * sm + oms * xc.x;
        o.x = pcen_one(xc.x, sm, alpha, delta, root, droot, root_is_half);
        sm = s * sm + oms * xc.y;
        o.y = pcen_one(xc.y, sm, alpha, delta, root, droot, root_is_half);
        sm = s * sm + oms * xc.z;
        o.z = pcen_one(xc.z, sm, alpha, delta, root, droot, root_is_half);
        sm = s * sm + oms * xc.w;
        o.w = pcen_one(xc.w, sm, alpha, delta, root, droot, root_is_half);

        *(f4*)(out + (size_t)row * T_LEN + off) = o;
        return;
    }

    // ---- Exact scan fallback (any s): one wave per row, others exit.
    if (cpos != 0) return;

    const float s2 = s * s;
    const float s3 = s2 * s;
    const float s4 = s2 * s2;
    const float m0 = s4;
    const float m1 = m0 * m0;
    const float m2 = m1 * m1;
    const float m3 = m2 * m2;
    const float m4 = m3 * m3;
    const float m5 = m4 * m4;
    const float s256 = m5 * m5;
    const float sp4i = fexp2(4.0f * (float)lane * flog2(s));

    const f4* __restrict__ xrow = (const f4*)(x + (size_t)row * T_LEN);
    f4* __restrict__ orow = (f4*)(out + (size_t)row * T_LEN);

    const int nchunks = T_LEN / 256;
    float carry = 0.0f;

    f4 xc = xrow[lane];
    for (int c = 0; c < nchunks; ++c) {
        f4 xn;
        if (c + 1 < nchunks) xn = xrow[(c + 1) * 64 + lane];

        float B = oms * (xc.x * s3 + xc.y * s2 + xc.z * s + xc.w);

        float P = B;
        float t;
        t = __shfl_up(P, 1);  if (lane >= 1)  P += m0 * t;
        t = __shfl_up(P, 2);  if (lane >= 2)  P += m1 * t;
        t = __shfl_up(P, 4);  if (lane >= 4)  P += m2 * t;
        t = __shfl_up(P, 8);  if (lane >= 8)  P += m3 * t;
        t = __shfl_up(P, 16); if (lane >= 16) P += m4 * t;
        t = __shfl_up(P, 32); if (lane >= 32) P += m5 * t;

        float X = __shfl_up(P, 1);
        if (lane == 0) X = 0.0f;

        float state = sp4i * carry + X;

        float smo0 = s * state + oms * xc.x;
        float smo1 = s * smo0  + oms * xc.y;
        float smo2 = s * smo1  + oms * xc.z;
        float smo3 = s * smo2  + oms * xc.w;

        float Plast = __shfl(P, 63);
        carry = s256 * carry + Plast;

        f4 o;
        o.x = pcen_one(xc.x, smo0, alpha, delta, root, droot, root_is_half);
        o.y = pcen_one(xc.y, smo1, alpha, delta, root, droot, root_is_half);
        o.z = pcen_one(xc.z, smo2, alpha, delta, root, droot, root_is_half);
        o.w = pcen_one(xc.w, smo3, alpha, delta, root, droot, root_is_half);
        orow[c * 64 + lane] = o;

        xc = xn;
    }
}

extern "C" void kernel_launch(void* const* d_in, const int* in_sizes, int n_in,
                              void* d_out, int out_size, void* d_ws, size_t ws_size,
                              hipStream_t stream) {
    const float* x       = (const float*)d_in[0];
    const float* alpha_p = (const float*)d_in[1];
    const float* delta_p = (const float*)d_in[2];
    const float* root_p  = (const float*)d_in[3];
    const float* sc_p    = (const float*)d_in[4];
    float* out = (float*)d_out;

    int nrows = in_sizes[0] / T_LEN;          // 8192 rows
    int nchunks_total = nrows * (T_LEN / CHUNK);
    int blocks = (nchunks_total + 3) / 4;     // 4 waves (chunks) per block

    pcen_kernel<<<blocks, 256, 0, stream>>>(x, alpha_p, delta_p, root_p, sc_p,
                                            out, nrows);
}

// Round 5
// 86.542 us; speedup vs baseline: 1.3923x; 1.1039x over previous
//
#include <hip/hip_runtime.h>

#define T_LEN 8192
#define CHUNK 256
#define FLOOR_C 1e-6f

typedef float f4 __attribute__((ext_vector_type(4)));

__device__ __forceinline__ float flog2(float v) { return __builtin_amdgcn_logf(v); }
__device__ __forceinline__ float fexp2(float v) { return __builtin_amdgcn_exp2f(v); }

__device__ __forceinline__ float pcen_one(float xv, float sm, float alpha,
                                          float delta, float root, float droot,
                                          bool root_is_half) {
    float st = fexp2(-alpha * flog2(FLOOR_C + sm));
    float inner = xv * st + delta;
    float pr = root_is_half ? sqrtf(inner) : fexp2(root * flog2(inner));
    return pr - droot;
}

__global__ __launch_bounds__(256) void pcen_kernel(
    const float* __restrict__ x,
    const float* __restrict__ alpha_p,
    const float* __restrict__ delta_p,
    const float* __restrict__ root_p,
    const float* __restrict__ sc_p,
    float* __restrict__ out,
    int nrows, int nblocks)
{
    const float alpha = alpha_p[0];
    const float delta = delta_p[0];
    const float root  = root_p[0];
    float s = sc_p[0];
    s = fminf(fmaxf(s, 0.001f), 0.999f);
    const float oms = 1.0f - s;

    const bool  root_is_half = (root == 0.5f);
    const float droot = root_is_half ? sqrtf(delta)
                                     : fexp2(root * flog2(delta));

    // XCD-aware bijective swizzle: HW round-robins blockIdx across 8 XCDs;
    // remap so each XCD owns a CONTIGUOUS range of chunks -> chunk-boundary
    // halo lines hit the local L2 instead of being refetched from HBM.
    // nblocks (65536) is divisible by 8 -> simple form is bijective.
    const int cpx = nblocks >> 3;
    const int bid = (int)blockIdx.x;
    const int swz = (nblocks % 8 == 0) ? (bid % 8) * cpx + (bid >> 3) : bid;

    const int wave = threadIdx.x >> 6;
    const int lane = threadIdx.x & 63;
    const int gid  = swz * 4 + wave;          // chunk id
    const int row  = gid >> 5;                // 32 chunks of 256 per row
    const int cpos = gid & 31;
    if (row >= nrows) return;

    if (s <= 0.08f) {
        // ---- Windowed path: smoothed[t] depends on <=12 predecessors to
        // fp32 precision (s^9 <= 0.08^9 ~ 1.3e-10). Zero-padded warm-up at
        // row start is EXACT (scan initial state is 0).
        const int off = cpos * CHUNK + lane * 4;      // float offset in row
        const float* p = x + (size_t)row * T_LEN + off;

        f4 xc  = *(const f4*)p;                       // own 4 elements
        f4 xm2 = (off >= 8) ? *(const f4*)(p - 8) : (f4){0.f, 0.f, 0.f, 0.f};
        f4 xm1 = (off >= 4) ? *(const f4*)(p - 4) : (f4){0.f, 0.f, 0.f, 0.f};

        // 8 warm-up EMA steps (halo), then 4 real steps with output
        float sm = 0.0f;
        sm = s * sm + oms * xm2.x;
        sm = s * sm + oms * xm2.y;
        sm = s * sm + oms * xm2.z;
        sm = s * sm + oms * xm2.w;
        sm = s * sm + oms * xm1.x;
        sm = s * sm + oms * xm1.y;
        sm = s * sm + oms * xm1.z;
        sm = s * sm + oms * xm1.w;

        f4 o;
        sm = s * sm + oms * xc.x;
        o.x = pcen_one(xc.x, sm, alpha, delta, root, droot, root_is_half);
        sm = s * sm + oms * xc.y;
        o.y = pcen_one(xc.y, sm, alpha, delta, root, droot, root_is_half);
        sm = s * sm + oms * xc.z;
        o.z = pcen_one(xc.z, sm, alpha, delta, root, droot, root_is_half);
        sm = s * sm + oms * xc.w;
        o.w = pcen_one(xc.w, sm, alpha, delta, root, droot, root_is_half);

        // store has zero reuse -> nontemporal keeps L2 free for halo reads
        __builtin_nontemporal_store(o, (f4*)(out + (size_t)row * T_LEN + off));
        return;
    }

    // ---- Exact scan fallback (any s): one wave per row, others exit.
    if (cpos != 0) return;

    const float s2 = s * s;
    const float s3 = s2 * s;
    const float s4 = s2 * s2;
    const float m0 = s4;
    const float m1 = m0 * m0;
    const float m2 = m1 * m1;
    const float m3 = m2 * m2;
    const float m4 = m3 * m3;
    const float m5 = m4 * m4;
    const float s256 = m5 * m5;
    const float sp4i = fexp2(4.0f * (float)lane * flog2(s));

    const f4* __restrict__ xrow = (const f4*)(x + (size_t)row * T_LEN);
    f4* __restrict__ orow = (f4*)(out + (size_t)row * T_LEN);

    const int nchunks = T_LEN / 256;
    float carry = 0.0f;

    f4 xc = xrow[lane];
    for (int c = 0; c < nchunks; ++c) {
        f4 xn;
        if (c + 1 < nchunks) xn = xrow[(c + 1) * 64 + lane];

        float B = oms * (xc.x * s3 + xc.y * s2 + xc.z * s + xc.w);

        float P = B;
        float t;
        t = __shfl_up(P, 1);  if (lane >= 1)  P += m0 * t;
        t = __shfl_up(P, 2);  if (lane >= 2)  P += m1 * t;
        t = __shfl_up(P, 4);  if (lane >= 4)  P += m2 * t;
        t = __shfl_up(P, 8);  if (lane >= 8)  P += m3 * t;
        t = __shfl_up(P, 16); if (lane >= 16) P += m4 * t;
        t = __shfl_up(P, 32); if (lane >= 32) P += m5 * t;

        float X = __shfl_up(P, 1);
        if (lane == 0) X = 0.0f;

        float state = sp4i * carry + X;

        float smo0 = s * state + oms * xc.x;
        float smo1 = s * smo0  + oms * xc.y;
        float smo2 = s * smo1  + oms * xc.z;
        float smo3 = s * smo2  + oms * xc.w;

        float Plast = __shfl(P, 63);
        carry = s256 * carry + Plast;

        f4 o;
        o.x = pcen_one(xc.x, smo0, alpha, delta, root, droot, root_is_half);
        o.y = pcen_one(xc.y, smo1, alpha, delta, root, droot, root_is_half);
        o.z = pcen_one(xc.z, smo2, alpha, delta, root, droot, root_is_half);
        o.w = pcen_one(xc.w, smo3, alpha, delta, root, droot, root_is_half);
        orow[c * 64 + lane] = o;

        xc = xn;
    }
}

extern "C" void kernel_launch(void* const* d_in, const int* in_sizes, int n_in,
                              void* d_out, int out_size, void* d_ws, size_t ws_size,
                              hipStream_t stream) {
    const float* x       = (const float*)d_in[0];
    const float* alpha_p = (const float*)d_in[1];
    const float* delta_p = (const float*)d_in[2];
    const float* root_p  = (const float*)d_in[3];
    const float* sc_p    = (const float*)d_in[4];
    float* out = (float*)d_out;

    int nrows = in_sizes[0] / T_LEN;          // 8192 rows
    int nchunks_total = nrows * (T_LEN / CHUNK);
    int blocks = (nchunks_total + 3) / 4;     // 4 waves (chunks) per block

    pcen_kernel<<<blocks, 256, 0, stream>>>(x, alpha_p, delta_p, root_p, sc_p,
                                            out, nrows, blocks);
}